// Round 2
// baseline (956.109 us; speedup 1.0000x reference)
//
#include <hip/hip_runtime.h>
#include <math.h>

// Problem constants (fixed by the reference)
#define N_NODES 50000
#define E_EDGES 1600000
#define R_REL   50
#define B_BAS   30
#define H_DIM   16
#define C_DIM   4

// ---------------------------------------------------------------------------
// k_w1: w1[r][n][h] = sum_b comp1[r][b] * basis1[b][n][h]
// one thread per (n,h); basis1 values held in registers, comp1 in LDS.
// ---------------------------------------------------------------------------
__global__ __launch_bounds__(256) void k_w1(const float* __restrict__ basis1,
                                            const float* __restrict__ comp1,
                                            float* __restrict__ w1) {
    __shared__ float s_comp[R_REL * B_BAS];
    for (int i = threadIdx.x; i < R_REL * B_BAS; i += blockDim.x)
        s_comp[i] = comp1[i];
    __syncthreads();

    const int idx = blockIdx.x * blockDim.x + threadIdx.x;  // over N*H
    const int NH = N_NODES * H_DIM;
    if (idx >= NH) return;

    float bv[B_BAS];
#pragma unroll
    for (int b = 0; b < B_BAS; ++b) bv[b] = basis1[b * NH + idx];

    for (int r = 0; r < R_REL; ++r) {
        float acc = 0.f;
#pragma unroll
        for (int b = 0; b < B_BAS; ++b) acc += s_comp[r * B_BAS + b] * bv[b];
        w1[(long long)r * NH + idx] = acc;
    }
}

// ---------------------------------------------------------------------------
// k_w2: w2[r][h][c] = sum_b comp2[r][b] * basis2[b][h][c]   (tiny: 3200 out)
// ---------------------------------------------------------------------------
__global__ __launch_bounds__(256) void k_w2(const float* __restrict__ basis2,
                                            const float* __restrict__ comp2,
                                            float* __restrict__ w2) {
    const int HC = H_DIM * C_DIM;  // 64
    for (int idx = threadIdx.x; idx < R_REL * HC; idx += blockDim.x) {
        int r = idx / HC;
        int hc = idx % HC;
        float acc = 0.f;
#pragma unroll
        for (int b = 0; b < B_BAS; ++b)
            acc += comp2[r * B_BAS + b] * basis2[b * HC + hc];
        w2[idx] = acc;
    }
}

// ---------------------------------------------------------------------------
// k_edge1: 4 lanes per edge. Each lane gathers one float4 of the 64B row
// w1[etype][src][:], atomicAdds into agg1[dst][:]; lane q==0 bumps cnt[dst].
// ---------------------------------------------------------------------------
__global__ __launch_bounds__(256) void k_edge1(const int* __restrict__ ei,
                                               const int* __restrict__ et,
                                               const float* __restrict__ w1,
                                               float* __restrict__ agg1,
                                               float* __restrict__ cnt) {
    const long long t = (long long)blockIdx.x * blockDim.x + threadIdx.x;
    const long long e = t >> 2;
    const int q = (int)(t & 3);
    if (e >= E_EDGES) return;

    const int src = ei[e];
    const int dst = ei[E_EDGES + e];
    const int r = et[e];

    const float4 v = *(const float4*)(w1 + (long long)r * (N_NODES * H_DIM)
                                      + src * H_DIM + q * 4);
    float* a = &agg1[dst * H_DIM + q * 4];
    atomicAdd(a + 0, v.x);
    atomicAdd(a + 1, v.y);
    atomicAdd(a + 2, v.z);
    atomicAdd(a + 3, v.w);
    if (q == 0) atomicAdd(&cnt[dst], 1.0f);
}

// ---------------------------------------------------------------------------
// k_x: x = relu(agg1 / max(cnt,1) + root1 + bias1)
// ---------------------------------------------------------------------------
__global__ __launch_bounds__(256) void k_x(const float* __restrict__ agg1,
                                           const float* __restrict__ cnt,
                                           const float* __restrict__ root1,
                                           const float* __restrict__ bias1,
                                           float* __restrict__ x) {
    const int idx = blockIdx.x * blockDim.x + threadIdx.x;
    if (idx >= N_NODES * H_DIM) return;
    const int n = idx >> 4;
    const int h = idx & 15;
    const float c = fmaxf(cnt[n], 1.0f);
    const float v = agg1[idx] / c + root1[idx] + bias1[h];
    x[idx] = fmaxf(v, 0.0f);
}

// ---------------------------------------------------------------------------
// k_edge2: one thread per edge. msg[c] = sum_h x[src][h] * w2[etype][h][c],
// atomicAdd into agg2[dst][c].
// ---------------------------------------------------------------------------
__global__ __launch_bounds__(256) void k_edge2(const int* __restrict__ ei,
                                               const int* __restrict__ et,
                                               const float* __restrict__ x,
                                               const float* __restrict__ w2,
                                               float* __restrict__ agg2) {
    const int e = blockIdx.x * blockDim.x + threadIdx.x;
    if (e >= E_EDGES) return;

    const int src = ei[e];
    const int dst = ei[E_EDGES + e];
    const int r = et[e];

    const float4* xp = (const float4*)(x + src * H_DIM);
    const float4* wp = (const float4*)(w2 + r * (H_DIM * C_DIM));

    float m0 = 0.f, m1 = 0.f, m2 = 0.f, m3 = 0.f;
#pragma unroll
    for (int hq = 0; hq < 4; ++hq) {
        const float4 xv = xp[hq];
        float4 w;
        w = wp[hq * 4 + 0];
        m0 += xv.x * w.x; m1 += xv.x * w.y; m2 += xv.x * w.z; m3 += xv.x * w.w;
        w = wp[hq * 4 + 1];
        m0 += xv.y * w.x; m1 += xv.y * w.y; m2 += xv.y * w.z; m3 += xv.y * w.w;
        w = wp[hq * 4 + 2];
        m0 += xv.z * w.x; m1 += xv.z * w.y; m2 += xv.z * w.z; m3 += xv.z * w.w;
        w = wp[hq * 4 + 3];
        m0 += xv.w * w.x; m1 += xv.w * w.y; m2 += xv.w * w.z; m3 += xv.w * w.w;
    }
    float* a = &agg2[dst * C_DIM];
    atomicAdd(a + 0, m0);
    atomicAdd(a + 1, m1);
    atomicAdd(a + 2, m2);
    atomicAdd(a + 3, m3);
}

// ---------------------------------------------------------------------------
// k_out: out = log_softmax(agg2/max(cnt,1) + x @ root2 + bias2)
// one thread per node (C=4 outputs each).
// ---------------------------------------------------------------------------
__global__ __launch_bounds__(256) void k_out(const float* __restrict__ agg2,
                                             const float* __restrict__ cnt,
                                             const float* __restrict__ x,
                                             const float* __restrict__ root2,
                                             const float* __restrict__ bias2,
                                             float* __restrict__ out) {
    const int n = blockIdx.x * blockDim.x + threadIdx.x;
    if (n >= N_NODES) return;

    const float c = fmaxf(cnt[n], 1.0f);
    float y0 = agg2[n * 4 + 0] / c + bias2[0];
    float y1 = agg2[n * 4 + 1] / c + bias2[1];
    float y2 = agg2[n * 4 + 2] / c + bias2[2];
    float y3 = agg2[n * 4 + 3] / c + bias2[3];

    const float4* xp = (const float4*)(x + n * H_DIM);
    const float4* rp = (const float4*)root2;  // [H][C] rows of 4
#pragma unroll
    for (int hq = 0; hq < 4; ++hq) {
        const float4 xv = xp[hq];
        float4 w;
        w = rp[hq * 4 + 0];
        y0 += xv.x * w.x; y1 += xv.x * w.y; y2 += xv.x * w.z; y3 += xv.x * w.w;
        w = rp[hq * 4 + 1];
        y0 += xv.y * w.x; y1 += xv.y * w.y; y2 += xv.y * w.z; y3 += xv.y * w.w;
        w = rp[hq * 4 + 2];
        y0 += xv.z * w.x; y1 += xv.z * w.y; y2 += xv.z * w.z; y3 += xv.z * w.w;
        w = rp[hq * 4 + 3];
        y0 += xv.w * w.x; y1 += xv.w * w.y; y2 += xv.w * w.z; y3 += xv.w * w.w;
    }

    // stable log_softmax over 4
    const float m = fmaxf(fmaxf(y0, y1), fmaxf(y2, y3));
    const float s = expf(y0 - m) + expf(y1 - m) + expf(y2 - m) + expf(y3 - m);
    const float lse = m + logf(s);
    out[n * 4 + 0] = y0 - lse;
    out[n * 4 + 1] = y1 - lse;
    out[n * 4 + 2] = y2 - lse;
    out[n * 4 + 3] = y3 - lse;
}

// ---------------------------------------------------------------------------
extern "C" void kernel_launch(void* const* d_in, const int* in_sizes, int n_in,
                              void* d_out, int out_size, void* d_ws, size_t ws_size,
                              hipStream_t stream) {
    const int*   edge_index = (const int*)d_in[0];   // [2, E]
    const int*   edge_type  = (const int*)d_in[1];   // [E]
    // d_in[2] = edge_norm (unused by reference)
    const float* basis1 = (const float*)d_in[3];     // [B, N, H]
    const float* comp1  = (const float*)d_in[4];     // [R, B]
    const float* root1  = (const float*)d_in[5];     // [N, H]
    const float* bias1  = (const float*)d_in[6];     // [H]
    const float* basis2 = (const float*)d_in[7];     // [B, H, C]
    const float* comp2  = (const float*)d_in[8];     // [R, B]
    const float* root2  = (const float*)d_in[9];     // [H, C]
    const float* bias2  = (const float*)d_in[10];    // [C]

    float* out = (float*)d_out;

    // Workspace layout (all 16B-aligned)
    char* ws = (char*)d_ws;
    const size_t sz_w1   = (size_t)R_REL * N_NODES * H_DIM * sizeof(float); // 160,000,000
    const size_t sz_agg1 = (size_t)N_NODES * H_DIM * sizeof(float);         //   3,200,000
    const size_t sz_x    = sz_agg1;                                         //   3,200,000
    const size_t sz_cnt  = (size_t)N_NODES * sizeof(float);                 //     200,000
    const size_t sz_w2   = (size_t)R_REL * H_DIM * C_DIM * sizeof(float);   //      12,800
    const size_t sz_agg2 = (size_t)N_NODES * C_DIM * sizeof(float);         //     800,000

    float* w1   = (float*)(ws);
    float* agg1 = (float*)(ws + sz_w1);
    float* x    = (float*)(ws + sz_w1 + sz_agg1);
    float* cnt  = (float*)(ws + sz_w1 + sz_agg1 + sz_x);
    float* w2   = (float*)(ws + sz_w1 + sz_agg1 + sz_x + sz_cnt);
    float* agg2 = (float*)(ws + sz_w1 + sz_agg1 + sz_x + sz_cnt + sz_w2);
    (void)ws_size;

    // Zero the whole accumulator region in one shot (agg1|x|cnt|w2|agg2).
    // x and w2 are overwritten before use; zeroing them too is harmless and
    // saves two extra graph nodes.
    hipMemsetAsync(agg1, 0, sz_agg1 + sz_x + sz_cnt + sz_w2 + sz_agg2, stream);

    // w1 / w2 precompute
    {
        const int total = N_NODES * H_DIM;
        k_w1<<<(total + 255) / 256, 256, 0, stream>>>(basis1, comp1, w1);
        k_w2<<<1, 256, 0, stream>>>(basis2, comp2, w2);
    }

    // layer-1 edge scatter (4 lanes per edge)
    {
        const long long total = (long long)E_EDGES * 4;  // 6.4M threads
        const int blocks = (int)((total + 255) / 256);
        k_edge1<<<blocks, 256, 0, stream>>>(edge_index, edge_type, w1, agg1, cnt);
    }

    // x = relu(mean + root1 + bias1)
    {
        const int total = N_NODES * H_DIM;
        k_x<<<(total + 255) / 256, 256, 0, stream>>>(agg1, cnt, root1, bias1, x);
    }

    // layer-2 edge transform + scatter
    {
        const int blocks = (E_EDGES + 255) / 256;
        k_edge2<<<blocks, 256, 0, stream>>>(edge_index, edge_type, x, w2, agg2);
    }

    // output + log_softmax
    {
        const int blocks = (N_NODES + 255) / 256;
        k_out<<<blocks, 256, 0, stream>>>(agg2, cnt, x, root2, bias2, out);
    }
}

// Round 3
// 514.179 us; speedup vs baseline: 1.8595x; 1.8595x over previous
//
#include <hip/hip_runtime.h>
#include <math.h>

// Problem constants (fixed by the reference)
#define N_NODES 50000
#define E_EDGES 1600000
#define R_REL   50
#define B_BAS   30
#define H_DIM   16
#define C_DIM   4
#define NH      (N_NODES * H_DIM)

// ---------------------------------------------------------------------------
// k_w1: w1[r][n][h] = sum_b comp1[r][b] * basis1[b][n][h]
// one thread per (n,h); basis1 values held in registers, comp1 in LDS.
// ---------------------------------------------------------------------------
__global__ __launch_bounds__(256) void k_w1(const float* __restrict__ basis1,
                                            const float* __restrict__ comp1,
                                            float* __restrict__ w1) {
    __shared__ float s_comp[R_REL * B_BAS];
    for (int i = threadIdx.x; i < R_REL * B_BAS; i += blockDim.x)
        s_comp[i] = comp1[i];
    __syncthreads();

    const int idx = blockIdx.x * blockDim.x + threadIdx.x;  // over N*H
    if (idx >= NH) return;

    float bv[B_BAS];
#pragma unroll
    for (int b = 0; b < B_BAS; ++b) bv[b] = basis1[b * NH + idx];

    for (int r = 0; r < R_REL; ++r) {
        float acc = 0.f;
#pragma unroll
        for (int b = 0; b < B_BAS; ++b) acc += s_comp[r * B_BAS + b] * bv[b];
        w1[(size_t)r * NH + idx] = acc;
    }
}

// ---------------------------------------------------------------------------
// k_w2: w2[r][h][c] = sum_b comp2[r][b] * basis2[b][h][c]   (tiny: 3200 out)
// ---------------------------------------------------------------------------
__global__ __launch_bounds__(256) void k_w2(const float* __restrict__ basis2,
                                            const float* __restrict__ comp2,
                                            float* __restrict__ w2) {
    const int HC = H_DIM * C_DIM;  // 64
    for (int idx = threadIdx.x; idx < R_REL * HC; idx += blockDim.x) {
        int r = idx / HC;
        int hc = idx % HC;
        float acc = 0.f;
#pragma unroll
        for (int b = 0; b < B_BAS; ++b)
            acc += comp2[r * B_BAS + b] * basis2[b * HC + hc];
        w2[idx] = acc;
    }
}

// ---------------------------------------------------------------------------
// CSR build step 1: per-dst edge histogram (int atomics, L2-resident table)
// ---------------------------------------------------------------------------
__global__ __launch_bounds__(256) void k_hist(const int* __restrict__ ei,
                                              int* __restrict__ cnt_i) {
    const int e = blockIdx.x * blockDim.x + threadIdx.x;
    if (e < E_EDGES) atomicAdd(&cnt_i[ei[E_EDGES + e]], 1);
}

// ---------------------------------------------------------------------------
// CSR build step 2a: per-block exclusive scan of counts; block totals to bsum
// ---------------------------------------------------------------------------
__global__ __launch_bounds__(256) void k_scan_part(const int* __restrict__ cnt_i,
                                                   int* __restrict__ part,
                                                   int* __restrict__ bsum) {
    const int i = blockIdx.x * 256 + threadIdx.x;
    const int lane = threadIdx.x & 63;
    const int wid = threadIdx.x >> 6;
    const int v = (i < N_NODES) ? cnt_i[i] : 0;
    int s = v;
#pragma unroll
    for (int d = 1; d < 64; d <<= 1) {
        int t = __shfl_up(s, d, 64);
        if (lane >= d) s += t;
    }
    __shared__ int wsum[4];
    if (lane == 63) wsum[wid] = s;
    __syncthreads();
    int woff = 0;
    for (int w = 0; w < wid; ++w) woff += wsum[w];
    if (i < N_NODES) part[i] = s - v + woff;
    if (threadIdx.x == 255) bsum[blockIdx.x] = woff + s;  // block total
}

// ---------------------------------------------------------------------------
// CSR build step 2b: exclusive scan of the 196 block totals (single block)
// ---------------------------------------------------------------------------
__global__ __launch_bounds__(256) void k_scan_tops(const int* __restrict__ bsum,
                                                   int* __restrict__ boff) {
    const int NB = (N_NODES + 255) / 256;  // 196
    const int lane = threadIdx.x & 63;
    const int wid = threadIdx.x >> 6;
    const int v = (threadIdx.x < NB) ? bsum[threadIdx.x] : 0;
    int s = v;
#pragma unroll
    for (int d = 1; d < 64; d <<= 1) {
        int t = __shfl_up(s, d, 64);
        if (lane >= d) s += t;
    }
    __shared__ int wsum[4];
    if (lane == 63) wsum[wid] = s;
    __syncthreads();
    int woff = 0;
    for (int w = 0; w < wid; ++w) woff += wsum[w];
    if (threadIdx.x < NB) boff[threadIdx.x] = s - v + woff;
}

// ---------------------------------------------------------------------------
// CSR build step 2c: combine -> off[] and a working cursor[] copy
// ---------------------------------------------------------------------------
__global__ __launch_bounds__(256) void k_scan_add(const int* __restrict__ part,
                                                  const int* __restrict__ boff,
                                                  int* __restrict__ off,
                                                  int* __restrict__ cursor) {
    const int i = blockIdx.x * 256 + threadIdx.x;
    if (i < N_NODES) {
        const int o = part[i] + boff[blockIdx.x];
        off[i] = o;
        cursor[i] = o;
    }
    if (i == 0) off[N_NODES] = E_EDGES;
}

// ---------------------------------------------------------------------------
// CSR build step 3: scatter packed (src | et<<16) records into dst buckets.
// src < 50000 fits 16 bits; et < 50 fits the high bits.
// ---------------------------------------------------------------------------
__global__ __launch_bounds__(256) void k_bucket(const int* __restrict__ ei,
                                                const int* __restrict__ et,
                                                int* __restrict__ cursor,
                                                unsigned* __restrict__ rec) {
    const int e = blockIdx.x * blockDim.x + threadIdx.x;
    if (e >= E_EDGES) return;
    const int src = ei[e];
    const int dst = ei[E_EDGES + e];
    const int r = et[e];
    const int pos = atomicAdd(&cursor[dst], 1);
    rec[pos] = (unsigned)src | ((unsigned)r << 16);
}

// ---------------------------------------------------------------------------
// k_agg1x: atomic-free layer-1 aggregation fused with x-epilogue.
// One wave per dst; lanes = (sub=lane>>4) edge-slot x (h=lane&15).
// x[dst][h] = relu( mean_e w1[et][src][h] + root1 + bias1 )
// ---------------------------------------------------------------------------
__global__ __launch_bounds__(256) void k_agg1x(const unsigned* __restrict__ rec,
                                               const int* __restrict__ off,
                                               const float* __restrict__ w1,
                                               const float* __restrict__ root1,
                                               const float* __restrict__ bias1,
                                               float* __restrict__ x) {
    const int wid = threadIdx.x >> 6;
    const int lane = threadIdx.x & 63;
    const int dst = blockIdx.x * 4 + wid;   // grid = 12500, 4 waves/block
    const int h = lane & 15;
    const int sub = lane >> 4;
    const int e0 = off[dst], e1 = off[dst + 1];

    float acc = 0.f;
    for (int e = e0 + sub; e < e1; e += 4) {
        const unsigned p = rec[e];
        const int src = (int)(p & 0xFFFFu);
        const int r = (int)(p >> 16);
        acc += w1[(size_t)r * NH + src * H_DIM + h];
    }
    acc += __shfl_xor(acc, 16, 64);
    acc += __shfl_xor(acc, 32, 64);

    if (sub == 0) {
        const float c = fmaxf((float)(e1 - e0), 1.f);
        const float v = acc / c + root1[dst * H_DIM + h] + bias1[h];
        x[dst * H_DIM + h] = fmaxf(v, 0.f);
    }
}

// ---------------------------------------------------------------------------
// k_agg2out: atomic-free layer-2 aggregation fused with root2 matvec and
// log_softmax. One wave per dst; per edge-slot 16 lanes each do 4 FMAs.
// ---------------------------------------------------------------------------
__global__ __launch_bounds__(256) void k_agg2out(const unsigned* __restrict__ rec,
                                                 const int* __restrict__ off,
                                                 const float* __restrict__ x,
                                                 const float* __restrict__ w2,
                                                 const float* __restrict__ root2,
                                                 const float* __restrict__ bias2,
                                                 float* __restrict__ out) {
    const int wid = threadIdx.x >> 6;
    const int lane = threadIdx.x & 63;
    const int dst = blockIdx.x * 4 + wid;
    const int h = lane & 15;
    const int sub = lane >> 4;
    const int e0 = off[dst], e1 = off[dst + 1];

    float a0 = 0.f, a1 = 0.f, a2 = 0.f, a3 = 0.f;
    for (int e = e0 + sub; e < e1; e += 4) {
        const unsigned p = rec[e];
        const int src = (int)(p & 0xFFFFu);
        const int r = (int)(p >> 16);
        const float xv = x[src * H_DIM + h];
        const float4 w = *(const float4*)(w2 + r * (H_DIM * C_DIM) + h * C_DIM);
        a0 += xv * w.x; a1 += xv * w.y; a2 += xv * w.z; a3 += xv * w.w;
    }
    // reduce over all 64 lanes (sums over both h and edge-slot)
#pragma unroll
    for (int d = 1; d < 64; d <<= 1) {
        a0 += __shfl_xor(a0, d, 64);
        a1 += __shfl_xor(a1, d, 64);
        a2 += __shfl_xor(a2, d, 64);
        a3 += __shfl_xor(a3, d, 64);
    }

    if (lane == 0) {
        const float c = fmaxf((float)(e1 - e0), 1.f);
        float y0 = a0 / c + bias2[0];
        float y1 = a1 / c + bias2[1];
        float y2 = a2 / c + bias2[2];
        float y3 = a3 / c + bias2[3];
#pragma unroll
        for (int hh = 0; hh < H_DIM; ++hh) {
            const float xv = x[dst * H_DIM + hh];
            const float4 w = *(const float4*)(root2 + hh * C_DIM);
            y0 += xv * w.x; y1 += xv * w.y; y2 += xv * w.z; y3 += xv * w.w;
        }
        const float m = fmaxf(fmaxf(y0, y1), fmaxf(y2, y3));
        const float s = expf(y0 - m) + expf(y1 - m) + expf(y2 - m) + expf(y3 - m);
        const float lse = m + logf(s);
        out[dst * 4 + 0] = y0 - lse;
        out[dst * 4 + 1] = y1 - lse;
        out[dst * 4 + 2] = y2 - lse;
        out[dst * 4 + 3] = y3 - lse;
    }
}

// ---------------------------------------------------------------------------
extern "C" void kernel_launch(void* const* d_in, const int* in_sizes, int n_in,
                              void* d_out, int out_size, void* d_ws, size_t ws_size,
                              hipStream_t stream) {
    const int*   edge_index = (const int*)d_in[0];   // [2, E]
    const int*   edge_type  = (const int*)d_in[1];   // [E]
    // d_in[2] = edge_norm (unused by reference)
    const float* basis1 = (const float*)d_in[3];     // [B, N, H]
    const float* comp1  = (const float*)d_in[4];     // [R, B]
    const float* root1  = (const float*)d_in[5];     // [N, H]
    const float* bias1  = (const float*)d_in[6];     // [H]
    const float* basis2 = (const float*)d_in[7];     // [B, H, C]
    const float* comp2  = (const float*)d_in[8];     // [R, B]
    const float* root2  = (const float*)d_in[9];     // [H, C]
    const float* bias2  = (const float*)d_in[10];    // [C]

    float* out = (float*)d_out;

    // ---- workspace layout (16B aligned blocks) ----
    char* ws = (char*)d_ws;
    size_t o = 0;
    auto take = [&](size_t bytes) { char* p = ws + o; o += (bytes + 15) & ~(size_t)15; return p; };

    float*    w1     = (float*)   take((size_t)R_REL * NH * sizeof(float));   // 160.0 MB
    unsigned* rec    = (unsigned*)take((size_t)E_EDGES * sizeof(unsigned));   //   6.4 MB
    float*    x      = (float*)   take((size_t)NH * sizeof(float));           //   3.2 MB
    int*      part   = (int*)x;   // alias: part dead before x is written
    int*      off    = (int*)     take((size_t)(N_NODES + 1) * sizeof(int));
    int*      cnt_i  = (int*)     take((size_t)N_NODES * sizeof(int));
    int*      cursor = (int*)     take((size_t)N_NODES * sizeof(int));
    float*    w2     = (float*)   take((size_t)R_REL * H_DIM * C_DIM * sizeof(float));
    int*      bsum   = (int*)     take(256 * sizeof(int));
    int*      boff   = (int*)     take(256 * sizeof(int));
    (void)ws_size;

    const int NB = (N_NODES + 255) / 256;  // 196 scan blocks

    // zero the histogram (ws is poisoned 0xAA before every timed call)
    hipMemsetAsync(cnt_i, 0, (size_t)N_NODES * sizeof(int), stream);

    // weight precompute
    k_w1<<<(NH + 255) / 256, 256, 0, stream>>>(basis1, comp1, w1);
    k_w2<<<1, 256, 0, stream>>>(basis2, comp2, w2);

    // CSR build: histogram -> scan -> bucket
    k_hist<<<(E_EDGES + 255) / 256, 256, 0, stream>>>(edge_index, cnt_i);
    k_scan_part<<<NB, 256, 0, stream>>>(cnt_i, part, bsum);
    k_scan_tops<<<1, 256, 0, stream>>>(bsum, boff);
    k_scan_add<<<NB, 256, 0, stream>>>(part, boff, off, cursor);
    k_bucket<<<(E_EDGES + 255) / 256, 256, 0, stream>>>(edge_index, edge_type, cursor, rec);

    // layer 1 (atomic-free) fused with relu/root/bias
    k_agg1x<<<N_NODES / 4, 256, 0, stream>>>(rec, off, w1, root1, bias1, x);

    // layer 2 (atomic-free) fused with root2 matvec + log_softmax
    k_agg2out<<<N_NODES / 4, 256, 0, stream>>>(rec, off, x, w2, root2, bias2, out);
}

// Round 5
// 451.390 us; speedup vs baseline: 2.1181x; 1.1391x over previous
//
#include <hip/hip_runtime.h>
#include <math.h>

// Problem constants (fixed by the reference)
#define N_NODES 50000
#define E_EDGES 1600000
#define R_REL   50
#define B_BAS   30
#define H_DIM   16
#define C_DIM   4
#define NH      (N_NODES * H_DIM)

// dst slicing for XCD-local scatter writes in k_bucket
#define NSLICE      8
#define SLICE_NODES (N_NODES / NSLICE)   // 6250

// ---------------------------------------------------------------------------
// k_front: fused independent front-end. Grid-partitioned:
//   blocks [0, 3125)      : w1[r][n][h] = sum_b comp1[r][b]*basis1[b][n][h]
//   blocks [3125, 9375)   : per-dst edge histogram (int atomics)
//   block  9375           : w2[r][h][c] = sum_b comp2[r][b]*basis2[b][h][c]
// These three have no mutual deps; fusing overlaps the BW-bound w1 stream
// with the atomic-bound histogram instead of serializing them.
// ---------------------------------------------------------------------------
#define W1_BLOCKS   (NH / 256)        // 3125
#define HIST_BLOCKS (E_EDGES / 256)   // 6250

__global__ __launch_bounds__(256) void k_front(const float* __restrict__ basis1,
                                               const float* __restrict__ comp1,
                                               float* __restrict__ w1,
                                               const float* __restrict__ basis2,
                                               const float* __restrict__ comp2,
                                               float* __restrict__ w2,
                                               const int* __restrict__ ei,
                                               int* __restrict__ cnt_i) {
    if (blockIdx.x < W1_BLOCKS) {
        __shared__ float s_comp[R_REL * B_BAS];
        for (int i = threadIdx.x; i < R_REL * B_BAS; i += 256)
            s_comp[i] = comp1[i];
        __syncthreads();

        const int idx = blockIdx.x * 256 + threadIdx.x;  // < NH exactly
        float bv[B_BAS];
#pragma unroll
        for (int b = 0; b < B_BAS; ++b) bv[b] = basis1[b * NH + idx];

        for (int r = 0; r < R_REL; ++r) {
            float acc = 0.f;
#pragma unroll
            for (int b = 0; b < B_BAS; ++b) acc += s_comp[r * B_BAS + b] * bv[b];
            w1[(size_t)r * NH + idx] = acc;
        }
    } else if (blockIdx.x < W1_BLOCKS + HIST_BLOCKS) {
        const int e = (blockIdx.x - W1_BLOCKS) * 256 + threadIdx.x;  // < E exactly
        atomicAdd(&cnt_i[ei[E_EDGES + e]], 1);
    } else {
        const int HC = H_DIM * C_DIM;  // 64
        for (int idx = threadIdx.x; idx < R_REL * HC; idx += 256) {
            const int r = idx / HC;
            const int hc = idx % HC;
            float acc = 0.f;
#pragma unroll
            for (int b = 0; b < B_BAS; ++b)
                acc += comp2[r * B_BAS + b] * basis2[b * HC + hc];
            w2[idx] = acc;
        }
    }
}

// ---------------------------------------------------------------------------
// CSR build step 2a: per-block exclusive scan of counts; block totals to bsum
// ---------------------------------------------------------------------------
__global__ __launch_bounds__(256) void k_scan_part(const int* __restrict__ cnt_i,
                                                   int* __restrict__ part,
                                                   int* __restrict__ bsum) {
    const int i = blockIdx.x * 256 + threadIdx.x;
    const int lane = threadIdx.x & 63;
    const int wid = threadIdx.x >> 6;
    const int v = (i < N_NODES) ? cnt_i[i] : 0;
    int s = v;
#pragma unroll
    for (int d = 1; d < 64; d <<= 1) {
        int t = __shfl_up(s, d, 64);
        if (lane >= d) s += t;
    }
    __shared__ int wsum[4];
    if (lane == 63) wsum[wid] = s;
    __syncthreads();
    int woff = 0;
    for (int w = 0; w < wid; ++w) woff += wsum[w];
    if (i < N_NODES) part[i] = s - v + woff;
    if (threadIdx.x == 255) bsum[blockIdx.x] = woff + s;  // block total
}

// ---------------------------------------------------------------------------
// CSR build step 2b: exclusive scan of the 196 block totals (single block)
// ---------------------------------------------------------------------------
__global__ __launch_bounds__(256) void k_scan_tops(const int* __restrict__ bsum,
                                                   int* __restrict__ boff) {
    const int NB = (N_NODES + 255) / 256;  // 196
    const int lane = threadIdx.x & 63;
    const int wid = threadIdx.x >> 6;
    const int v = (threadIdx.x < NB) ? bsum[threadIdx.x] : 0;
    int s = v;
#pragma unroll
    for (int d = 1; d < 64; d <<= 1) {
        int t = __shfl_up(s, d, 64);
        if (lane >= d) s += t;
    }
    __shared__ int wsum[4];
    if (lane == 63) wsum[wid] = s;
    __syncthreads();
    int woff = 0;
    for (int w = 0; w < wid; ++w) woff += wsum[w];
    if (threadIdx.x < NB) boff[threadIdx.x] = s - v + woff;
}

// ---------------------------------------------------------------------------
// CSR build step 2c: combine -> off[] and a working cursor[] copy
// ---------------------------------------------------------------------------
__global__ __launch_bounds__(256) void k_scan_add(const int* __restrict__ part,
                                                  const int* __restrict__ boff,
                                                  int* __restrict__ off,
                                                  int* __restrict__ cursor) {
    const int i = blockIdx.x * 256 + threadIdx.x;
    if (i < N_NODES) {
        const int o = part[i] + boff[blockIdx.x];
        off[i] = o;
        cursor[i] = o;
    }
    if (i == 0) off[N_NODES] = E_EDGES;
}

// ---------------------------------------------------------------------------
// CSR build step 3 (XCD-sliced): scatter packed (src | et<<16) records into
// dst buckets. blockIdx = chunk*8 + slice; a block only handles edges whose
// dst is in its slice's 6250-node range. Since block dispatch round-robins
// XCDs (blockIdx%8 ~ XCD), all writers of a given ~800KB rec region live on
// one XCD -> dirty lines coalesce ~16 scatter writes in that XCD's L2 before
// writeback (was: 1 write/line -> 100MB HBM write traffic).
// ---------------------------------------------------------------------------
__global__ __launch_bounds__(256) void k_bucket(const int* __restrict__ ei,
                                                const int* __restrict__ et,
                                                int* __restrict__ cursor,
                                                unsigned* __restrict__ rec) {
    const int chunk = blockIdx.x >> 3;
    const int slice = blockIdx.x & (NSLICE - 1);
    const int lo = slice * SLICE_NODES;

    const int e = chunk * 256 + threadIdx.x;
    if (e >= E_EDGES) return;
    const int dst = ei[E_EDGES + e];
    if ((unsigned)(dst - lo) >= (unsigned)SLICE_NODES) return;

    const int src = ei[e];
    const int r = et[e];
    const int pos = atomicAdd(&cursor[dst], 1);
    rec[pos] = (unsigned)src | ((unsigned)r << 16);
}

// ---------------------------------------------------------------------------
// k_agg1x: atomic-free layer-1 aggregation fused with x-epilogue.
// One wave per dst; lanes = (sub=lane>>4) edge-slot x (h=lane&15).
// x[dst][h] = relu( mean_e w1[et][src][h] + root1 + bias1 )
// ---------------------------------------------------------------------------
__global__ __launch_bounds__(256) void k_agg1x(const unsigned* __restrict__ rec,
                                               const int* __restrict__ off,
                                               const float* __restrict__ w1,
                                               const float* __restrict__ root1,
                                               const float* __restrict__ bias1,
                                               float* __restrict__ x) {
    const int wid = threadIdx.x >> 6;
    const int lane = threadIdx.x & 63;
    const int dst = blockIdx.x * 4 + wid;   // grid = 12500, 4 waves/block
    const int h = lane & 15;
    const int sub = lane >> 4;
    const int e0 = off[dst], e1 = off[dst + 1];

    float acc = 0.f;
    for (int e = e0 + sub; e < e1; e += 4) {
        const unsigned p = rec[e];
        const int src = (int)(p & 0xFFFFu);
        const int r = (int)(p >> 16);
        acc += w1[(size_t)r * NH + src * H_DIM + h];
    }
    acc += __shfl_xor(acc, 16, 64);
    acc += __shfl_xor(acc, 32, 64);

    if (sub == 0) {
        const float c = fmaxf((float)(e1 - e0), 1.f);
        const float v = acc / c + root1[dst * H_DIM + h] + bias1[h];
        x[dst * H_DIM + h] = fmaxf(v, 0.f);
    }
}

// ---------------------------------------------------------------------------
// k_agg2out: atomic-free layer-2 aggregation fused with root2 matvec and
// log_softmax. One wave per dst; per edge-slot 16 lanes each do 4 FMAs.
// ---------------------------------------------------------------------------
__global__ __launch_bounds__(256) void k_agg2out(const unsigned* __restrict__ rec,
                                                 const int* __restrict__ off,
                                                 const float* __restrict__ x,
                                                 const float* __restrict__ w2,
                                                 const float* __restrict__ root2,
                                                 const float* __restrict__ bias2,
                                                 float* __restrict__ out) {
    const int wid = threadIdx.x >> 6;
    const int lane = threadIdx.x & 63;
    const int dst = blockIdx.x * 4 + wid;
    const int h = lane & 15;
    const int sub = lane >> 4;
    const int e0 = off[dst], e1 = off[dst + 1];

    float a0 = 0.f, a1 = 0.f, a2 = 0.f, a3 = 0.f;
    for (int e = e0 + sub; e < e1; e += 4) {
        const unsigned p = rec[e];
        const int src = (int)(p & 0xFFFFu);
        const int r = (int)(p >> 16);
        const float xv = x[src * H_DIM + h];
        const float4 w = *(const float4*)(w2 + r * (H_DIM * C_DIM) + h * C_DIM);
        a0 += xv * w.x; a1 += xv * w.y; a2 += xv * w.z; a3 += xv * w.w;
    }
    // reduce over all 64 lanes (sums over both h and edge-slot)
#pragma unroll
    for (int d = 1; d < 64; d <<= 1) {
        a0 += __shfl_xor(a0, d, 64);
        a1 += __shfl_xor(a1, d, 64);
        a2 += __shfl_xor(a2, d, 64);
        a3 += __shfl_xor(a3, d, 64);
    }

    if (lane == 0) {
        const float c = fmaxf((float)(e1 - e0), 1.f);
        float y0 = a0 / c + bias2[0];
        float y1 = a1 / c + bias2[1];
        float y2 = a2 / c + bias2[2];
        float y3 = a3 / c + bias2[3];
#pragma unroll
        for (int hh = 0; hh < H_DIM; ++hh) {
            const float xv = x[dst * H_DIM + hh];
            const float4 w = *(const float4*)(root2 + hh * C_DIM);
            y0 += xv * w.x; y1 += xv * w.y; y2 += xv * w.z; y3 += xv * w.w;
        }
        const float m = fmaxf(fmaxf(y0, y1), fmaxf(y2, y3));
        const float s = expf(y0 - m) + expf(y1 - m) + expf(y2 - m) + expf(y3 - m);
        const float lse = m + logf(s);
        out[dst * 4 + 0] = y0 - lse;
        out[dst * 4 + 1] = y1 - lse;
        out[dst * 4 + 2] = y2 - lse;
        out[dst * 4 + 3] = y3 - lse;
    }
}

// ---------------------------------------------------------------------------
extern "C" void kernel_launch(void* const* d_in, const int* in_sizes, int n_in,
                              void* d_out, int out_size, void* d_ws, size_t ws_size,
                              hipStream_t stream) {
    const int*   edge_index = (const int*)d_in[0];   // [2, E]
    const int*   edge_type  = (const int*)d_in[1];   // [E]
    // d_in[2] = edge_norm (unused by reference)
    const float* basis1 = (const float*)d_in[3];     // [B, N, H]
    const float* comp1  = (const float*)d_in[4];     // [R, B]
    const float* root1  = (const float*)d_in[5];     // [N, H]
    const float* bias1  = (const float*)d_in[6];     // [H]
    const float* basis2 = (const float*)d_in[7];     // [B, H, C]
    const float* comp2  = (const float*)d_in[8];     // [R, B]
    const float* root2  = (const float*)d_in[9];     // [H, C]
    const float* bias2  = (const float*)d_in[10];    // [C]

    float* out = (float*)d_out;

    // ---- workspace layout (16B aligned blocks) ----
    char* ws = (char*)d_ws;
    size_t o = 0;
    auto take = [&](size_t bytes) { char* p = ws + o; o += (bytes + 15) & ~(size_t)15; return p; };

    float*    w1     = (float*)   take((size_t)R_REL * NH * sizeof(float));   // 160.0 MB
    unsigned* rec    = (unsigned*)take((size_t)E_EDGES * sizeof(unsigned));   //   6.4 MB
    float*    x      = (float*)   take((size_t)NH * sizeof(float));           //   3.2 MB
    int*      part   = (int*)x;   // alias: part dead before x is written
    int*      off    = (int*)     take((size_t)(N_NODES + 1) * sizeof(int));
    int*      cnt_i  = (int*)     take((size_t)N_NODES * sizeof(int));
    int*      cursor = (int*)     take((size_t)N_NODES * sizeof(int));
    float*    w2     = (float*)   take((size_t)R_REL * H_DIM * C_DIM * sizeof(float));
    int*      bsum   = (int*)     take(256 * sizeof(int));
    int*      boff   = (int*)     take(256 * sizeof(int));
    (void)ws_size;

    const int NB = (N_NODES + 255) / 256;  // 196 scan blocks

    // zero the histogram (ws is poisoned 0xAA before every timed call)
    hipMemsetAsync(cnt_i, 0, (size_t)N_NODES * sizeof(int), stream);

    // fused front-end: w1 precompute || dst histogram || w2 precompute
    k_front<<<W1_BLOCKS + HIST_BLOCKS + 1, 256, 0, stream>>>(
        basis1, comp1, w1, basis2, comp2, w2, edge_index, cnt_i);

    // CSR build: scan -> bucket (XCD-sliced scatter)
    k_scan_part<<<NB, 256, 0, stream>>>(cnt_i, part, bsum);
    k_scan_tops<<<1, 256, 0, stream>>>(bsum, boff);
    k_scan_add<<<NB, 256, 0, stream>>>(part, boff, off, cursor);
    {
        const int chunks = (E_EDGES + 255) / 256;  // 6250
        k_bucket<<<chunks * NSLICE, 256, 0, stream>>>(edge_index, edge_type, cursor, rec);
    }

    // layer 1 (atomic-free) fused with relu/root/bias
    k_agg1x<<<N_NODES / 4, 256, 0, stream>>>(rec, off, w1, root1, bias1, x);

    // layer 2 (atomic-free) fused with root2 matvec + log_softmax
    k_agg2out<<<N_NODES / 4, 256, 0, stream>>>(rec, off, x, w2, root2, bias2, out);
}

// Round 6
// 437.757 us; speedup vs baseline: 2.1841x; 1.0311x over previous
//
#include <hip/hip_runtime.h>
#include <math.h>

// Problem constants (fixed by the reference)
#define N_NODES 50000
#define E_EDGES 1600000
#define R_REL   50
#define B_BAS   30
#define H_DIM   16
#define C_DIM   4
#define NH      (N_NODES * H_DIM)

// dst slicing for XCD-local scatter writes in k_bucket
#define NSLICE      8
#define SLICE_NODES (N_NODES / NSLICE)   // 6250

// k_front geometry: every block does BOTH a w1 slice and a hist slice, so the
// BW-bound w1 write stream is spread across ALL CUs (round-5 grid-partition
// gave w1 only 1/3 of the machine -> 2.0 TB/s; this should reach ~5-6 TB/s).
#define FRONT_BLOCKS (NH / 256)            // 3125
#define EDGES_PER_FRONT (E_EDGES / FRONT_BLOCKS)  // 512

// ---------------------------------------------------------------------------
// k_front: fused w1 precompute + dst histogram, interleaved per block.
//   hist: 512 edges/block, 2 atomics/thread, fired first (no dependency).
//   w1:   w1[r][n][h] = sum_b comp1[r][b]*basis1[b][n][h], 256 cols/block.
// ---------------------------------------------------------------------------
__global__ __launch_bounds__(256) void k_front(const float* __restrict__ basis1,
                                               const float* __restrict__ comp1,
                                               float* __restrict__ w1,
                                               const int* __restrict__ ei,
                                               int* __restrict__ cnt_i) {
    // ---- histogram share: fire-and-forget atomics ----
    {
        const int ebase = blockIdx.x * EDGES_PER_FRONT + threadIdx.x;
        atomicAdd(&cnt_i[ei[E_EDGES + ebase]], 1);
        atomicAdd(&cnt_i[ei[E_EDGES + ebase + 256]], 1);
    }

    // ---- w1 share ----
    __shared__ float s_comp[R_REL * B_BAS];
    for (int i = threadIdx.x; i < R_REL * B_BAS; i += 256)
        s_comp[i] = comp1[i];
    __syncthreads();

    const int idx = blockIdx.x * 256 + threadIdx.x;  // < NH exactly
    float bv[B_BAS];
#pragma unroll
    for (int b = 0; b < B_BAS; ++b) bv[b] = basis1[b * NH + idx];

    for (int r = 0; r < R_REL; ++r) {
        float acc = 0.f;
#pragma unroll
        for (int b = 0; b < B_BAS; ++b) acc += s_comp[r * B_BAS + b] * bv[b];
        w1[(size_t)r * NH + idx] = acc;
    }
}

// ---------------------------------------------------------------------------
// CSR build step 2a: per-block exclusive scan of counts; block totals to bsum
// ---------------------------------------------------------------------------
__global__ __launch_bounds__(256) void k_scan_part(const int* __restrict__ cnt_i,
                                                   int* __restrict__ part,
                                                   int* __restrict__ bsum) {
    const int i = blockIdx.x * 256 + threadIdx.x;
    const int lane = threadIdx.x & 63;
    const int wid = threadIdx.x >> 6;
    const int v = (i < N_NODES) ? cnt_i[i] : 0;
    int s = v;
#pragma unroll
    for (int d = 1; d < 64; d <<= 1) {
        int t = __shfl_up(s, d, 64);
        if (lane >= d) s += t;
    }
    __shared__ int wsum[4];
    if (lane == 63) wsum[wid] = s;
    __syncthreads();
    int woff = 0;
    for (int w = 0; w < wid; ++w) woff += wsum[w];
    if (i < N_NODES) part[i] = s - v + woff;
    if (threadIdx.x == 255) bsum[blockIdx.x] = woff + s;  // block total
}

// ---------------------------------------------------------------------------
// CSR build step 2b: exclusive scan of the 196 block totals (single block).
// Also computes w2 (tiny, independent) to keep it off other kernels.
// ---------------------------------------------------------------------------
__global__ __launch_bounds__(256) void k_scan_tops(const int* __restrict__ bsum,
                                                   int* __restrict__ boff,
                                                   const float* __restrict__ basis2,
                                                   const float* __restrict__ comp2,
                                                   float* __restrict__ w2) {
    const int NB = (N_NODES + 255) / 256;  // 196
    const int lane = threadIdx.x & 63;
    const int wid = threadIdx.x >> 6;
    const int v = (threadIdx.x < NB) ? bsum[threadIdx.x] : 0;
    int s = v;
#pragma unroll
    for (int d = 1; d < 64; d <<= 1) {
        int t = __shfl_up(s, d, 64);
        if (lane >= d) s += t;
    }
    __shared__ int wsum[4];
    if (lane == 63) wsum[wid] = s;
    __syncthreads();
    int woff = 0;
    for (int w = 0; w < wid; ++w) woff += wsum[w];
    if (threadIdx.x < NB) boff[threadIdx.x] = s - v + woff;

    // w2[r][h][c] = sum_b comp2[r][b] * basis2[b][h][c]   (3200 outputs)
    const int HC = H_DIM * C_DIM;  // 64
    for (int idx = threadIdx.x; idx < R_REL * HC; idx += 256) {
        const int r = idx / HC;
        const int hc = idx % HC;
        float acc = 0.f;
#pragma unroll
        for (int b = 0; b < B_BAS; ++b)
            acc += comp2[r * B_BAS + b] * basis2[b * HC + hc];
        w2[idx] = acc;
    }
}

// ---------------------------------------------------------------------------
// CSR build step 2c: combine -> off[] and a working cursor[] copy
// ---------------------------------------------------------------------------
__global__ __launch_bounds__(256) void k_scan_add(const int* __restrict__ part,
                                                  const int* __restrict__ boff,
                                                  int* __restrict__ off,
                                                  int* __restrict__ cursor) {
    const int i = blockIdx.x * 256 + threadIdx.x;
    if (i < N_NODES) {
        const int o = part[i] + boff[blockIdx.x];
        off[i] = o;
        cursor[i] = o;
    }
    if (i == 0) off[N_NODES] = E_EDGES;
}

// ---------------------------------------------------------------------------
// CSR build step 3 (XCD-sliced): scatter packed (src | et<<16) records into
// dst buckets. blockIdx = chunk*8 + slice; a block only handles edges whose
// dst is in its slice's 6250-node range (blockIdx%8 ~ XCD -> rec slice writes
// coalesce in one XCD's L2). Streaming ei/et reads are non-temporal so they
// don't evict the dirty rec lines before neighbors coalesce into them.
// ---------------------------------------------------------------------------
__global__ __launch_bounds__(256) void k_bucket(const int* __restrict__ ei,
                                                const int* __restrict__ et,
                                                int* __restrict__ cursor,
                                                unsigned* __restrict__ rec) {
    const int chunk = blockIdx.x >> 3;
    const int slice = blockIdx.x & (NSLICE - 1);
    const int lo = slice * SLICE_NODES;

    const int e = chunk * 256 + threadIdx.x;
    if (e >= E_EDGES) return;
    const int dst = __builtin_nontemporal_load(&ei[E_EDGES + e]);
    if ((unsigned)(dst - lo) >= (unsigned)SLICE_NODES) return;

    const int src = __builtin_nontemporal_load(&ei[e]);
    const int r = __builtin_nontemporal_load(&et[e]);
    const int pos = atomicAdd(&cursor[dst], 1);
    rec[pos] = (unsigned)src | ((unsigned)r << 16);
}

// ---------------------------------------------------------------------------
// k_agg1x: atomic-free layer-1 aggregation fused with x-epilogue.
// One wave per dst; lanes = (sub=lane>>4) edge-slot x (h=lane&15).
// x[dst][h] = relu( mean_e w1[et][src][h] + root1 + bias1 )
// ---------------------------------------------------------------------------
__global__ __launch_bounds__(256) void k_agg1x(const unsigned* __restrict__ rec,
                                               const int* __restrict__ off,
                                               const float* __restrict__ w1,
                                               const float* __restrict__ root1,
                                               const float* __restrict__ bias1,
                                               float* __restrict__ x) {
    const int wid = threadIdx.x >> 6;
    const int lane = threadIdx.x & 63;
    const int dst = blockIdx.x * 4 + wid;   // grid = 12500, 4 waves/block
    const int h = lane & 15;
    const int sub = lane >> 4;
    const int e0 = off[dst], e1 = off[dst + 1];

    float acc = 0.f;
    for (int e = e0 + sub; e < e1; e += 4) {
        const unsigned p = rec[e];
        const int src = (int)(p & 0xFFFFu);
        const int r = (int)(p >> 16);
        acc += w1[(size_t)r * NH + src * H_DIM + h];
    }
    acc += __shfl_xor(acc, 16, 64);
    acc += __shfl_xor(acc, 32, 64);

    if (sub == 0) {
        const float c = fmaxf((float)(e1 - e0), 1.f);
        const float v = acc / c + root1[dst * H_DIM + h] + bias1[h];
        x[dst * H_DIM + h] = fmaxf(v, 0.f);
    }
}

// ---------------------------------------------------------------------------
// k_agg2out: atomic-free layer-2 aggregation fused with root2 matvec and
// log_softmax. One wave per dst; per edge-slot 16 lanes each do 4 FMAs.
// ---------------------------------------------------------------------------
__global__ __launch_bounds__(256) void k_agg2out(const unsigned* __restrict__ rec,
                                                 const int* __restrict__ off,
                                                 const float* __restrict__ x,
                                                 const float* __restrict__ w2,
                                                 const float* __restrict__ root2,
                                                 const float* __restrict__ bias2,
                                                 float* __restrict__ out) {
    const int wid = threadIdx.x >> 6;
    const int lane = threadIdx.x & 63;
    const int dst = blockIdx.x * 4 + wid;
    const int h = lane & 15;
    const int sub = lane >> 4;
    const int e0 = off[dst], e1 = off[dst + 1];

    float a0 = 0.f, a1 = 0.f, a2 = 0.f, a3 = 0.f;
    for (int e = e0 + sub; e < e1; e += 4) {
        const unsigned p = rec[e];
        const int src = (int)(p & 0xFFFFu);
        const int r = (int)(p >> 16);
        const float xv = x[src * H_DIM + h];
        const float4 w = *(const float4*)(w2 + r * (H_DIM * C_DIM) + h * C_DIM);
        a0 += xv * w.x; a1 += xv * w.y; a2 += xv * w.z; a3 += xv * w.w;
    }
    // reduce over all 64 lanes (sums over both h and edge-slot)
#pragma unroll
    for (int d = 1; d < 64; d <<= 1) {
        a0 += __shfl_xor(a0, d, 64);
        a1 += __shfl_xor(a1, d, 64);
        a2 += __shfl_xor(a2, d, 64);
        a3 += __shfl_xor(a3, d, 64);
    }

    if (lane == 0) {
        const float c = fmaxf((float)(e1 - e0), 1.f);
        float y0 = a0 / c + bias2[0];
        float y1 = a1 / c + bias2[1];
        float y2 = a2 / c + bias2[2];
        float y3 = a3 / c + bias2[3];
#pragma unroll
        for (int hh = 0; hh < H_DIM; ++hh) {
            const float xv = x[dst * H_DIM + hh];
            const float4 w = *(const float4*)(root2 + hh * C_DIM);
            y0 += xv * w.x; y1 += xv * w.y; y2 += xv * w.z; y3 += xv * w.w;
        }
        const float m = fmaxf(fmaxf(y0, y1), fmaxf(y2, y3));
        const float s = expf(y0 - m) + expf(y1 - m) + expf(y2 - m) + expf(y3 - m);
        const float lse = m + logf(s);
        out[dst * 4 + 0] = y0 - lse;
        out[dst * 4 + 1] = y1 - lse;
        out[dst * 4 + 2] = y2 - lse;
        out[dst * 4 + 3] = y3 - lse;
    }
}

// ---------------------------------------------------------------------------
extern "C" void kernel_launch(void* const* d_in, const int* in_sizes, int n_in,
                              void* d_out, int out_size, void* d_ws, size_t ws_size,
                              hipStream_t stream) {
    const int*   edge_index = (const int*)d_in[0];   // [2, E]
    const int*   edge_type  = (const int*)d_in[1];   // [E]
    // d_in[2] = edge_norm (unused by reference)
    const float* basis1 = (const float*)d_in[3];     // [B, N, H]
    const float* comp1  = (const float*)d_in[4];     // [R, B]
    const float* root1  = (const float*)d_in[5];     // [N, H]
    const float* bias1  = (const float*)d_in[6];     // [H]
    const float* basis2 = (const float*)d_in[7];     // [B, H, C]
    const float* comp2  = (const float*)d_in[8];     // [R, B]
    const float* root2  = (const float*)d_in[9];     // [H, C]
    const float* bias2  = (const float*)d_in[10];    // [C]

    float* out = (float*)d_out;

    // ---- workspace layout (16B aligned blocks) ----
    char* ws = (char*)d_ws;
    size_t o = 0;
    auto take = [&](size_t bytes) { char* p = ws + o; o += (bytes + 15) & ~(size_t)15; return p; };

    float*    w1     = (float*)   take((size_t)R_REL * NH * sizeof(float));   // 160.0 MB
    unsigned* rec    = (unsigned*)take((size_t)E_EDGES * sizeof(unsigned));   //   6.4 MB
    float*    x      = (float*)   take((size_t)NH * sizeof(float));           //   3.2 MB
    int*      part   = (int*)x;   // alias: part dead before x is written
    int*      off    = (int*)     take((size_t)(N_NODES + 1) * sizeof(int));
    int*      cnt_i  = (int*)     take((size_t)N_NODES * sizeof(int));
    int*      cursor = (int*)     take((size_t)N_NODES * sizeof(int));
    float*    w2     = (float*)   take((size_t)R_REL * H_DIM * C_DIM * sizeof(float));
    int*      bsum   = (int*)     take(256 * sizeof(int));
    int*      boff   = (int*)     take(256 * sizeof(int));
    (void)ws_size;

    const int NB = (N_NODES + 255) / 256;  // 196 scan blocks

    // zero the histogram (ws is poisoned 0xAA before every timed call)
    hipMemsetAsync(cnt_i, 0, (size_t)N_NODES * sizeof(int), stream);

    // fused front-end: every block does hist share + w1 share (uniform BW)
    k_front<<<FRONT_BLOCKS, 256, 0, stream>>>(basis1, comp1, w1, edge_index, cnt_i);

    // CSR build: scan (+w2 piggyback) -> bucket (XCD-sliced scatter)
    k_scan_part<<<NB, 256, 0, stream>>>(cnt_i, part, bsum);
    k_scan_tops<<<1, 256, 0, stream>>>(bsum, boff, basis2, comp2, w2);
    k_scan_add<<<NB, 256, 0, stream>>>(part, boff, off, cursor);
    {
        const int chunks = (E_EDGES + 255) / 256;  // 6250
        k_bucket<<<chunks * NSLICE, 256, 0, stream>>>(edge_index, edge_type, cursor, rec);
    }

    // layer 1 (atomic-free) fused with relu/root/bias
    k_agg1x<<<N_NODES / 4, 256, 0, stream>>>(rec, off, w1, root1, bias1, x);

    // layer 2 (atomic-free) fused with root2 matvec + log_softmax
    k_agg2out<<<N_NODES / 4, 256, 0, stream>>>(rec, off, x, w2, root2, bias2, out);
}

// Round 7
// 426.929 us; speedup vs baseline: 2.2395x; 1.0254x over previous
//
#include <hip/hip_runtime.h>
#include <math.h>

// Problem constants (fixed by the reference)
#define N_NODES 50000
#define E_EDGES 1600000
#define R_REL   50
#define B_BAS   30
#define H_DIM   16
#define C_DIM   4
#define NH      (N_NODES * H_DIM)

// dst slicing for XCD-local scatter writes in k_bucket
#define NSLICE      8
#define SLICE_NODES (N_NODES / NSLICE)   // 6250

#define FRONT_BLOCKS (NH / 256)                   // 3125
#define EDGES_PER_FRONT (E_EDGES / FRONT_BLOCKS)  // 512

// ---------------------------------------------------------------------------
// k_front: fused w1 precompute + dst histogram, interleaved per block.
//   hist: 512 edges/block, 2 atomics/thread, fired first (no dependency).
//   w1:   w1[r][n][h] = sum_b comp1[r][b]*basis1[b][n][h], 256 cols/block.
// comp1 is read DIRECTLY from global with thread-uniform indices -> compiler
// emits s_load (SGPR operand to v_fmac). Round-6 version staged comp1 in LDS:
// 1500 ds_read_b32/thread was the issue-bound limiter (123us, VALU 36%).
// ---------------------------------------------------------------------------
__global__ __launch_bounds__(256) void k_front(const float* __restrict__ basis1,
                                               const float* __restrict__ comp1,
                                               float* __restrict__ w1,
                                               const int* __restrict__ ei,
                                               int* __restrict__ cnt_i) {
    // ---- histogram share: fire-and-forget atomics ----
    {
        const int ebase = blockIdx.x * EDGES_PER_FRONT + threadIdx.x;
        atomicAdd(&cnt_i[ei[E_EDGES + ebase]], 1);
        atomicAdd(&cnt_i[ei[E_EDGES + ebase + 256]], 1);
    }

    // ---- w1 share ----
    const int idx = blockIdx.x * 256 + threadIdx.x;  // < NH exactly
    float bv[B_BAS];
#pragma unroll
    for (int b = 0; b < B_BAS; ++b) bv[b] = basis1[b * NH + idx];

    for (int r = 0; r < R_REL; ++r) {
        float acc = 0.f;
#pragma unroll
        for (int b = 0; b < B_BAS; ++b) acc += comp1[r * B_BAS + b] * bv[b];
        w1[(size_t)r * NH + idx] = acc;
    }
}

// ---------------------------------------------------------------------------
// CSR build step 2a: per-block exclusive scan of counts; block totals to bsum
// ---------------------------------------------------------------------------
__global__ __launch_bounds__(256) void k_scan_part(const int* __restrict__ cnt_i,
                                                   int* __restrict__ part,
                                                   int* __restrict__ bsum) {
    const int i = blockIdx.x * 256 + threadIdx.x;
    const int lane = threadIdx.x & 63;
    const int wid = threadIdx.x >> 6;
    const int v = (i < N_NODES) ? cnt_i[i] : 0;
    int s = v;
#pragma unroll
    for (int d = 1; d < 64; d <<= 1) {
        int t = __shfl_up(s, d, 64);
        if (lane >= d) s += t;
    }
    __shared__ int wsum[4];
    if (lane == 63) wsum[wid] = s;
    __syncthreads();
    int woff = 0;
    for (int w = 0; w < wid; ++w) woff += wsum[w];
    if (i < N_NODES) part[i] = s - v + woff;
    if (threadIdx.x == 255) bsum[blockIdx.x] = woff + s;  // block total
}

// ---------------------------------------------------------------------------
// CSR build step 2b: exclusive scan of the 196 block totals (single block).
// Also computes w2 (tiny, independent) to keep it off other kernels.
// ---------------------------------------------------------------------------
__global__ __launch_bounds__(256) void k_scan_tops(const int* __restrict__ bsum,
                                                   int* __restrict__ boff,
                                                   const float* __restrict__ basis2,
                                                   const float* __restrict__ comp2,
                                                   float* __restrict__ w2) {
    const int NB = (N_NODES + 255) / 256;  // 196
    const int lane = threadIdx.x & 63;
    const int wid = threadIdx.x >> 6;
    const int v = (threadIdx.x < NB) ? bsum[threadIdx.x] : 0;
    int s = v;
#pragma unroll
    for (int d = 1; d < 64; d <<= 1) {
        int t = __shfl_up(s, d, 64);
        if (lane >= d) s += t;
    }
    __shared__ int wsum[4];
    if (lane == 63) wsum[wid] = s;
    __syncthreads();
    int woff = 0;
    for (int w = 0; w < wid; ++w) woff += wsum[w];
    if (threadIdx.x < NB) boff[threadIdx.x] = s - v + woff;

    // w2[r][h][c] = sum_b comp2[r][b] * basis2[b][h][c]   (3200 outputs)
    const int HC = H_DIM * C_DIM;  // 64
    for (int idx = threadIdx.x; idx < R_REL * HC; idx += 256) {
        const int r = idx / HC;
        const int hc = idx % HC;
        float acc = 0.f;
#pragma unroll
        for (int b = 0; b < B_BAS; ++b)
            acc += comp2[r * B_BAS + b] * basis2[b * HC + hc];
        w2[idx] = acc;
    }
}

// ---------------------------------------------------------------------------
// CSR build step 2c: combine -> off[] and a working cursor[] copy
// ---------------------------------------------------------------------------
__global__ __launch_bounds__(256) void k_scan_add(const int* __restrict__ part,
                                                  const int* __restrict__ boff,
                                                  int* __restrict__ off,
                                                  int* __restrict__ cursor) {
    const int i = blockIdx.x * 256 + threadIdx.x;
    if (i < N_NODES) {
        const int o = part[i] + boff[blockIdx.x];
        off[i] = o;
        cursor[i] = o;
    }
    if (i == 0) off[N_NODES] = E_EDGES;
}

// ---------------------------------------------------------------------------
// CSR build step 3 (XCD-sliced): scatter packed (src | et<<16) records into
// dst buckets. blockIdx = chunk*8 + slice; a block only handles edges whose
// dst is in its slice's 6250-node range (blockIdx%8 ~ XCD -> rec slice writes
// coalesce in one XCD's L2). Streaming ei/et reads are non-temporal so they
// don't evict the dirty rec lines before neighbors coalesce into them.
// ---------------------------------------------------------------------------
__global__ __launch_bounds__(256) void k_bucket(const int* __restrict__ ei,
                                                const int* __restrict__ et,
                                                int* __restrict__ cursor,
                                                unsigned* __restrict__ rec) {
    const int chunk = blockIdx.x >> 3;
    const int slice = blockIdx.x & (NSLICE - 1);
    const int lo = slice * SLICE_NODES;

    const int e = chunk * 256 + threadIdx.x;
    if (e >= E_EDGES) return;
    const int dst = __builtin_nontemporal_load(&ei[E_EDGES + e]);
    if ((unsigned)(dst - lo) >= (unsigned)SLICE_NODES) return;

    const int src = __builtin_nontemporal_load(&ei[e]);
    const int r = __builtin_nontemporal_load(&et[e]);
    const int pos = atomicAdd(&cursor[dst], 1);
    rec[pos] = (unsigned)src | ((unsigned)r << 16);
}

// ---------------------------------------------------------------------------
// k_agg1x: atomic-free layer-1 aggregation fused with x-epilogue.
// One wave per dst; lanes = (sub=lane>>4) edge-slot x (h=lane&15).
// x[dst][h] = relu( mean_e w1[et][src][h] + root1 + bias1 )
// ---------------------------------------------------------------------------
__global__ __launch_bounds__(256) void k_agg1x(const unsigned* __restrict__ rec,
                                               const int* __restrict__ off,
                                               const float* __restrict__ w1,
                                               const float* __restrict__ root1,
                                               const float* __restrict__ bias1,
                                               float* __restrict__ x) {
    const int wid = threadIdx.x >> 6;
    const int lane = threadIdx.x & 63;
    const int dst = blockIdx.x * 4 + wid;   // grid = 12500, 4 waves/block
    const int h = lane & 15;
    const int sub = lane >> 4;
    const int e0 = off[dst], e1 = off[dst + 1];

    float acc = 0.f;
    for (int e = e0 + sub; e < e1; e += 4) {
        const unsigned p = rec[e];
        const int src = (int)(p & 0xFFFFu);
        const int r = (int)(p >> 16);
        acc += w1[(size_t)r * NH + src * H_DIM + h];
    }
    acc += __shfl_xor(acc, 16, 64);
    acc += __shfl_xor(acc, 32, 64);

    if (sub == 0) {
        const float c = fmaxf((float)(e1 - e0), 1.f);
        const float v = acc / c + root1[dst * H_DIM + h] + bias1[h];
        x[dst * H_DIM + h] = fmaxf(v, 0.f);
    }
}

// ---------------------------------------------------------------------------
// k_agg2out: atomic-free layer-2 aggregation fused with root2 matvec and
// log_softmax. One wave per dst; per edge-slot 16 lanes each do 4 FMAs.
// ---------------------------------------------------------------------------
__global__ __launch_bounds__(256) void k_agg2out(const unsigned* __restrict__ rec,
                                                 const int* __restrict__ off,
                                                 const float* __restrict__ x,
                                                 const float* __restrict__ w2,
                                                 const float* __restrict__ root2,
                                                 const float* __restrict__ bias2,
                                                 float* __restrict__ out) {
    const int wid = threadIdx.x >> 6;
    const int lane = threadIdx.x & 63;
    const int dst = blockIdx.x * 4 + wid;
    const int h = lane & 15;
    const int sub = lane >> 4;
    const int e0 = off[dst], e1 = off[dst + 1];

    float a0 = 0.f, a1 = 0.f, a2 = 0.f, a3 = 0.f;
    for (int e = e0 + sub; e < e1; e += 4) {
        const unsigned p = rec[e];
        const int src = (int)(p & 0xFFFFu);
        const int r = (int)(p >> 16);
        const float xv = x[src * H_DIM + h];
        const float4 w = *(const float4*)(w2 + r * (H_DIM * C_DIM) + h * C_DIM);
        a0 += xv * w.x; a1 += xv * w.y; a2 += xv * w.z; a3 += xv * w.w;
    }
    // reduce over all 64 lanes (sums over both h and edge-slot)
#pragma unroll
    for (int d = 1; d < 64; d <<= 1) {
        a0 += __shfl_xor(a0, d, 64);
        a1 += __shfl_xor(a1, d, 64);
        a2 += __shfl_xor(a2, d, 64);
        a3 += __shfl_xor(a3, d, 64);
    }

    if (lane == 0) {
        const float c = fmaxf((float)(e1 - e0), 1.f);
        float y0 = a0 / c + bias2[0];
        float y1 = a1 / c + bias2[1];
        float y2 = a2 / c + bias2[2];
        float y3 = a3 / c + bias2[3];
#pragma unroll
        for (int hh = 0; hh < H_DIM; ++hh) {
            const float xv = x[dst * H_DIM + hh];
            const float4 w = *(const float4*)(root2 + hh * C_DIM);
            y0 += xv * w.x; y1 += xv * w.y; y2 += xv * w.z; y3 += xv * w.w;
        }
        const float m = fmaxf(fmaxf(y0, y1), fmaxf(y2, y3));
        const float s = expf(y0 - m) + expf(y1 - m) + expf(y2 - m) + expf(y3 - m);
        const float lse = m + logf(s);
        out[dst * 4 + 0] = y0 - lse;
        out[dst * 4 + 1] = y1 - lse;
        out[dst * 4 + 2] = y2 - lse;
        out[dst * 4 + 3] = y3 - lse;
    }
}

// ---------------------------------------------------------------------------
extern "C" void kernel_launch(void* const* d_in, const int* in_sizes, int n_in,
                              void* d_out, int out_size, void* d_ws, size_t ws_size,
                              hipStream_t stream) {
    const int*   edge_index = (const int*)d_in[0];   // [2, E]
    const int*   edge_type  = (const int*)d_in[1];   // [E]
    // d_in[2] = edge_norm (unused by reference)
    const float* basis1 = (const float*)d_in[3];     // [B, N, H]
    const float* comp1  = (const float*)d_in[4];     // [R, B]
    const float* root1  = (const float*)d_in[5];     // [N, H]
    const float* bias1  = (const float*)d_in[6];     // [H]
    const float* basis2 = (const float*)d_in[7];     // [B, H, C]
    const float* comp2  = (const float*)d_in[8];     // [R, B]
    const float* root2  = (const float*)d_in[9];     // [H, C]
    const float* bias2  = (const float*)d_in[10];    // [C]

    float* out = (float*)d_out;

    // ---- workspace layout (16B aligned blocks) ----
    char* ws = (char*)d_ws;
    size_t o = 0;
    auto take = [&](size_t bytes) { char* p = ws + o; o += (bytes + 15) & ~(size_t)15; return p; };

    float*    w1     = (float*)   take((size_t)R_REL * NH * sizeof(float));   // 160.0 MB
    unsigned* rec    = (unsigned*)take((size_t)E_EDGES * sizeof(unsigned));   //   6.4 MB
    float*    x      = (float*)   take((size_t)NH * sizeof(float));           //   3.2 MB
    int*      part   = (int*)x;   // alias: part dead before x is written
    int*      off    = (int*)     take((size_t)(N_NODES + 1) * sizeof(int));
    int*      cnt_i  = (int*)     take((size_t)N_NODES * sizeof(int));
    int*      cursor = (int*)     take((size_t)N_NODES * sizeof(int));
    float*    w2     = (float*)   take((size_t)R_REL * H_DIM * C_DIM * sizeof(float));
    int*      bsum   = (int*)     take(256 * sizeof(int));
    int*      boff   = (int*)     take(256 * sizeof(int));
    (void)ws_size;

    const int NB = (N_NODES + 255) / 256;  // 196 scan blocks

    // zero the histogram (ws is poisoned 0xAA before every timed call)
    hipMemsetAsync(cnt_i, 0, (size_t)N_NODES * sizeof(int), stream);

    // fused front-end: every block does hist share + w1 share (uniform BW)
    k_front<<<FRONT_BLOCKS, 256, 0, stream>>>(basis1, comp1, w1, edge_index, cnt_i);

    // CSR build: scan (+w2 piggyback) -> bucket (XCD-sliced scatter)
    k_scan_part<<<NB, 256, 0, stream>>>(cnt_i, part, bsum);
    k_scan_tops<<<1, 256, 0, stream>>>(bsum, boff, basis2, comp2, w2);
    k_scan_add<<<NB, 256, 0, stream>>>(part, boff, off, cursor);
    {
        const int chunks = (E_EDGES + 255) / 256;  // 6250
        k_bucket<<<chunks * NSLICE, 256, 0, stream>>>(edge_index, edge_type, cursor, rec);
    }

    // layer 1 (atomic-free) fused with relu/root/bias
    k_agg1x<<<N_NODES / 4, 256, 0, stream>>>(rec, off, w1, root1, bias1, x);

    // layer 2 (atomic-free) fused with root2 matvec + log_softmax
    k_agg2out<<<N_NODES / 4, 256, 0, stream>>>(rec, off, x, w2, root2, bias2, out);
}